// Round 5
// baseline (267.907 us; speedup 1.0000x reference)
//
#include <hip/hip_runtime.h>
#include <math.h>

// Fused self-attention, B=8, S=2048, D=64 fp32; outputs context [8,2048,64] and
// full attention filter [8,2048,2048].
//
// Round-11: exp-once relay. The two-pass structure (stats then emit) computed
// QK^T and exp TWICE. Now:
//   K0 attn_prep : K->fp16 [b][s][d], V->fp16 transposed [b][d][s], zero Ctx.
//   K1 attn_pexp : QK^T once; p'' = exp2(s*log2e - 4) (mask -> 0) stored as
//                  fp16 to Pws [8][2048][2048] (64 MiB ws, L2/L3-resident
//                  relay); per-row partial sums to part[4][16384].
//                  The -4 bias gives 16x fp16 headroom and cancels exactly in
//                  the normalization (Filt = p''/sum(p''), O = (p''V)/sum(p'')).
//   K2 attn_emit2: no QK^T, no exp, no LDS. Reads p'' fragments (16B/lane);
//                  the SAME registers feed the Filt store (f32(p'')*invl,
//                  nontemporal) and the PV MFMA A-operand. O scaled by invl,
//                  accumulated to Ctx via unsafeAtomicAdd (4-way splits).
//   merge folded into emit2 prologue (reads 4 partials per row).
// No barriers in hot kernels; all fragment reads direct-global (L2-resident).
// Cross-run dur_us noise is ~±40 us (R1 vs R10: identical structure, 167 vs
// 240) -> judge by per-dispatch counters.

typedef _Float16 f16x8 __attribute__((ext_vector_type(8)));
typedef _Float16 f16x4 __attribute__((ext_vector_type(4)));
typedef float f32x4 __attribute__((ext_vector_type(4)));

#define BATCH 8
#define SDIM 2048
#define DDIM 64
#define KBLK 64
#define NBLK (SDIM / KBLK)      // 32
#define KSPLIT 4
#define BPW (NBLK / KSPLIT)     // 8 key-blocks per WG
#define NROWS (BATCH * SDIM)    // 16384
#define QSCALE 0.180336878f     // 0.125 * log2(e): QK^T result is s*log2e
#define EBIAS 4.0f              // p'' = 2^(acc - 4); cancels in normalization
#define KSTR 72                 // LDS row stride in shorts (144 B, 16B-aligned)

__device__ __forceinline__ float fidx(const float4& v, int i) {
    return ((const float*)&v)[i];
}

// ======== K0: K->fp16, V->fp16 transposed, zero Ctx.  256 WGs ========
__global__ __launch_bounds__(256, 4)
void attn_prep(const float* __restrict__ Kg, const float* __restrict__ Vg,
               short* __restrict__ Kbf, short* __restrict__ VTbf,
               float* __restrict__ Ctx)
{
    __shared__ short VTlds[DDIM][KSTR];

    const int wg = blockIdx.x;           // 256 = 8 batches x 32 key-blocks
    const int b = wg & 7;
    const int kbase = (wg >> 3) * KBLK;
    const int tid = threadIdx.x;

    const float* Kb = Kg + (size_t)b * SDIM * DDIM;
    const float* Vb = Vg + (size_t)b * SDIM * DDIM;

    // K convert: thread t -> key=t>>2, 16 d's
    {
        const int key = tid >> 2, doff = (tid & 3) * 16;
        const float* src = Kb + (size_t)(kbase + key) * DDIM + doff;
        float4 f0 = *(const float4*)(src);
        float4 f1 = *(const float4*)(src + 4);
        float4 f2 = *(const float4*)(src + 8);
        float4 f3 = *(const float4*)(src + 12);
        f16x8 p0, p1;
        p0[0]=(_Float16)f0.x; p0[1]=(_Float16)f0.y; p0[2]=(_Float16)f0.z; p0[3]=(_Float16)f0.w;
        p0[4]=(_Float16)f1.x; p0[5]=(_Float16)f1.y; p0[6]=(_Float16)f1.z; p0[7]=(_Float16)f1.w;
        p1[0]=(_Float16)f2.x; p1[1]=(_Float16)f2.y; p1[2]=(_Float16)f2.z; p1[3]=(_Float16)f2.w;
        p1[4]=(_Float16)f3.x; p1[5]=(_Float16)f3.y; p1[6]=(_Float16)f3.z; p1[7]=(_Float16)f3.w;
        short* dst = Kbf + ((size_t)b * SDIM + kbase + key) * DDIM + doff;
        *(f16x8*)dst = p0;
        *(f16x8*)(dst + 8) = p1;
    }

    // V transpose via LDS: thread t loads 4 keys x 4 d's, writes transposed
    {
        const int sv_d0 = (tid & 15) * 4, sv_k0 = (tid >> 4) * 4;
        float4 vreg[4];
        #pragma unroll
        for (int i = 0; i < 4; ++i)
            vreg[i] = *(const float4*)(Vb + (size_t)(kbase + sv_k0 + i) * DDIM + sv_d0);
        #pragma unroll
        for (int dd = 0; dd < 4; ++dd) {
            f16x4 pv;
            pv[0] = (_Float16)fidx(vreg[0], dd);
            pv[1] = (_Float16)fidx(vreg[1], dd);
            pv[2] = (_Float16)fidx(vreg[2], dd);
            pv[3] = (_Float16)fidx(vreg[3], dd);
            *(f16x4*)&VTlds[sv_d0 + dd][sv_k0] = pv;
        }
    }
    __syncthreads();
    {
        const int d = tid >> 2, koff = (tid & 3) * 16;
        f16x8 a = *(const f16x8*)&VTlds[d][koff];
        f16x8 c = *(const f16x8*)&VTlds[d][koff + 8];
        short* dst = VTbf + ((size_t)b * DDIM + d) * SDIM + kbase + koff;
        *(f16x8*)dst = a;
        *(f16x8*)(dst + 8) = c;
    }

    // zero this WG's 16 KB slice of Ctx (4 MB / 256 WGs)
    {
        float4* dst = (float4*)Ctx + (size_t)wg * 1024;
        for (int i = tid; i < 1024; i += 256) dst[i] = make_float4(0.f, 0.f, 0.f, 0.f);
    }
}

// ====== K1: QK^T once -> p'' fp16 relay + partial row sums ======
// Swapped MFMA: C[key=quad*4+r][query=col].
__global__ __launch_bounds__(256, 4)
void attn_pexp(const short* __restrict__ Kbf, const float* __restrict__ Qg,
               const int* __restrict__ Mg, short* __restrict__ Pws,
               float* __restrict__ part)
{
    const int wg = blockIdx.x;
    const int b = wg & 7;
    const int qt = (wg >> 3) & 31;
    const int sp = wg >> 8;
    const int tid = threadIdx.x;
    const int w = tid >> 6, lane = tid & 63, col = lane & 15, quad = lane >> 4;

    // persistent Q fragment (B operand); 0.125*log2e folded in
    f16x8 aq[2];
    {
        const float* qsrc = Qg + ((size_t)b * SDIM + qt * 64 + w * 16 + col) * DDIM + quad * 8;
        #pragma unroll
        for (int c = 0; c < 2; ++c) {
            float4 f0 = *(const float4*)(qsrc + c * 32);
            float4 f1 = *(const float4*)(qsrc + c * 32 + 4);
            f16x8 a;
            a[0]=(_Float16)(f0.x*QSCALE); a[1]=(_Float16)(f0.y*QSCALE); a[2]=(_Float16)(f0.z*QSCALE); a[3]=(_Float16)(f0.w*QSCALE);
            a[4]=(_Float16)(f1.x*QSCALE); a[5]=(_Float16)(f1.y*QSCALE); a[6]=(_Float16)(f1.z*QSCALE); a[7]=(_Float16)(f1.w*QSCALE);
            aq[c] = a;
        }
    }

    const int kb0 = sp * BPW * KBLK;
    const short* Kb = Kbf + (size_t)b * SDIM * DDIM;
    const int*   Mb = Mg + (size_t)b * SDIM;
    // this lane's P'' row (query = col)
    short* Prow = Pws + ((size_t)b * SDIM + qt * 64 + w * 16 + col) * SDIM;

    float lsum = 0.0f;
    for (int kb = 0; kb < BPW; ++kb) {
        const int kbase = kb0 + kb * KBLK;
        f16x8 kf[4][2];
        #pragma unroll
        for (int t = 0; t < 4; ++t) {
            const short* ks = Kb + (size_t)(kbase + t * 16 + col) * DDIM + quad * 8;
            kf[t][0] = *(const f16x8*)ks;
            kf[t][1] = *(const f16x8*)(ks + 32);
        }
        #pragma unroll
        for (int t = 0; t < 4; ++t) {
            f32x4 acc = {0.f, 0.f, 0.f, 0.f};
            acc = __builtin_amdgcn_mfma_f32_16x16x32_f16(kf[t][0], aq[0], acc, 0, 0, 0);
            acc = __builtin_amdgcn_mfma_f32_16x16x32_f16(kf[t][1], aq[1], acc, 0, 0, 0);
            int4 mq = *(const int4*)(Mb + kbase + t * 16 + quad * 4);
            float e0 = mq.x ? 0.0f : exp2f(acc[0] - EBIAS);
            float e1 = mq.y ? 0.0f : exp2f(acc[1] - EBIAS);
            float e2 = mq.z ? 0.0f : exp2f(acc[2] - EBIAS);
            float e3 = mq.w ? 0.0f : exp2f(acc[3] - EBIAS);
            lsum += e0 + e1 + e2 + e3;
            f16x4 pb;
            pb[0] = (_Float16)e0; pb[1] = (_Float16)e1;
            pb[2] = (_Float16)e2; pb[3] = (_Float16)e3;
            // 4 consecutive keys of this query's row -> 8B store (cached: L2/L3 relay)
            *(f16x4*)&Prow[kbase + t * 16 + quad * 4] = pb;
        }
    }

    // each lane holds a quarter of this query's keys; sum across quads
    lsum += __shfl_xor(lsum, 16);
    lsum += __shfl_xor(lsum, 32);
    if (quad == 0)
        part[(size_t)sp * NROWS + (size_t)b * SDIM + qt * 64 + w * 16 + col] = lsum;
}

// ======= K2: emit filter + context from the p'' relay (no QK^T, no exp) =======
__global__ __launch_bounds__(256, 4)
void attn_emit2(const short* __restrict__ Pws, const short* __restrict__ VTbf,
                const float* __restrict__ part, float* __restrict__ Ctx,
                float* __restrict__ Filt)
{
    const int wg = blockIdx.x;
    const int b = wg & 7;
    const int qt = (wg >> 3) & 31;
    const int sp = wg >> 8;
    const int tid = threadIdx.x;
    const int w = tid >> 6, lane = tid & 63, col = lane & 15, quad = lane >> 4;

    const short* VTb = VTbf + (size_t)b * DDIM * SDIM;
    float* Ctxb  = Ctx  + (size_t)b * SDIM * DDIM;
    float* Filtb = Filt + (size_t)b * SDIM * SDIM;

    // invl for the Filt row this lane emits (query = col)
    const int qrow_f = qt * 64 + w * 16 + col;
    float invf;
    {
        const size_t row = (size_t)b * SDIM + qrow_f;
        invf = 1.0f / (part[row] + part[NROWS + row] +
                       part[2 * NROWS + row] + part[3 * NROWS + row]);
    }
    // invl for the 4 context rows this lane accumulates (query = quad*4+r)
    float invo[4];
    #pragma unroll
    for (int r = 0; r < 4; ++r) {
        const size_t row = (size_t)b * SDIM + qt * 64 + w * 16 + quad * 4 + r;
        invo[r] = 1.0f / (part[row] + part[NROWS + row] +
                          part[2 * NROWS + row] + part[3 * NROWS + row]);
    }

    const int kb0 = sp * BPW * KBLK;
    const short* Prow = Pws + ((size_t)b * SDIM + qrow_f) * SDIM;

    f32x4 Oacc[4];
    #pragma unroll
    for (int dt = 0; dt < 4; ++dt) Oacc[dt] = (f32x4){0.f, 0.f, 0.f, 0.f};

    for (int kb = 0; kb < BPW; ++kb) {
        const int kbase = kb0 + kb * KBLK;

        // ---- loads first: p'' fragments (A-operand AND Filt source) + VT ----
        f16x8 pp[2];
        #pragma unroll
        for (int c = 0; c < 2; ++c)
            pp[c] = *(const f16x8*)&Prow[kbase + c * 32 + quad * 8];
        f16x8 vt[2][4];
        #pragma unroll
        for (int c = 0; c < 2; ++c)
            #pragma unroll
            for (int dt = 0; dt < 4; ++dt)
                vt[c][dt] = *(const f16x8*)(VTb + (size_t)(dt * 16 + col) * SDIM + kbase + c * 32 + quad * 8);

        // ---- Filt = f32(p'') * invl, nontemporal dwordx4 pairs ----
        #pragma unroll
        for (int c = 0; c < 2; ++c) {
            f32x4 lo, hi;
            lo[0] = (float)pp[c][0] * invf; lo[1] = (float)pp[c][1] * invf;
            lo[2] = (float)pp[c][2] * invf; lo[3] = (float)pp[c][3] * invf;
            hi[0] = (float)pp[c][4] * invf; hi[1] = (float)pp[c][5] * invf;
            hi[2] = (float)pp[c][6] * invf; hi[3] = (float)pp[c][7] * invf;
            float* fdst = &Filtb[(size_t)qrow_f * SDIM + kbase + c * 32 + quad * 8];
            __builtin_nontemporal_store(lo, (f32x4*)fdst);
            __builtin_nontemporal_store(hi, (f32x4*)(fdst + 4));
        }

        // ---- O += p'' * V (A-operand straight from the relay registers) ----
        #pragma unroll
        for (int c = 0; c < 2; ++c) {
            #pragma unroll
            for (int dt = 0; dt < 4; ++dt)
                Oacc[dt] = __builtin_amdgcn_mfma_f32_16x16x32_f16(pp[c], vt[c][dt], Oacc[dt], 0, 0, 0);
        }
    }

    // accumulate context (scale by this row's invl; 4-way split contention)
    #pragma unroll
    for (int dt = 0; dt < 4; ++dt) {
        #pragma unroll
        for (int r = 0; r < 4; ++r) {
            unsafeAtomicAdd(&Ctxb[(size_t)(qt * 64 + w * 16 + quad * 4 + r) * DDIM + dt * 16 + col],
                            Oacc[dt][r] * invo[r]);
        }
    }
}

extern "C" void kernel_launch(void* const* d_in, const int* in_sizes, int n_in,
                              void* d_out, int out_size, void* d_ws, size_t ws_size,
                              hipStream_t stream) {
    // setup_inputs order: key, query, value, query_attention_mask
    const float* Kg = (const float*)d_in[0];
    const float* Qg = (const float*)d_in[1];
    const float* Vg = (const float*)d_in[2];
    const int*   Mg = (const int*)d_in[3];
    float* Ctx  = (float*)d_out;                                   // [8,2048,64]
    float* Filt = (float*)d_out + (size_t)BATCH * SDIM * DDIM;     // [8,2048,2048]

    // workspace: Kbf 2 MB | VTbf 2 MB | part 256 KB | Pws 64 MB
    short* Kbf  = (short*)d_ws;                                    // [8][2048][64] fp16
    short* VTbf = Kbf + (size_t)BATCH * SDIM * DDIM;               // [8][64][2048] fp16
    float* part = (float*)(VTbf + (size_t)BATCH * DDIM * SDIM);    // [4][16384]
    short* Pws  = (short*)(part + (size_t)KSPLIT * NROWS);         // [8][2048][2048] fp16

    attn_prep<<<dim3(BATCH * NBLK), dim3(256), 0, stream>>>(Kg, Vg, Kbf, VTbf, Ctx);
    // 8 batches x 32 qtiles x 4 key-splits = 1024 WGs (sp = wg>>8 decode)
    attn_pexp<<<dim3(BATCH * NBLK * KSPLIT), dim3(256), 0, stream>>>(Kbf, Qg, Mg, Pws, part);
    attn_emit2<<<dim3(BATCH * NBLK * KSPLIT), dim3(256), 0, stream>>>(Pws, VTbf, part, Ctx, Filt);
}

// Round 6
// 253.218 us; speedup vs baseline: 1.0580x; 1.0580x over previous
//
#include <hip/hip_runtime.h>
#include <math.h>

// Fused self-attention, B=8, S=2048, D=64 fp32; outputs context [8,2048,64] and
// full attention filter [8,2048,2048].
//
// Round-12: fix emit2's Filt store write-amplification (measured 259.8 MB
// written vs 128 MiB payload = 2.0x). R11 stored lo/hi f32x4 at c*32+quad*8:
// each instruction writes 16B pieces at 32B stride, so every 64B HBM granule
// is half-written by two different nt instructions -> 2x amplification
// (nontemporal stores don't merge across instructions). R7's pattern
// (t*16+quad*4: quads form one contiguous 64B run per row per instruction)
// measured NO amplification. Restore it:
//   - emit2 loads the relay in TWO mappings: pp4[t] = f16x4 @ t*16+quad*4
//     (feeds the Filt store, R7 pattern) and pp[c] = f16x8 @ c*32+quad*8
//     (feeds the PV MFMA A-operand). Extra 32 MiB of Pws reads are L2/L3-hits.
//   - all loads issue before the nt stores (stores stay in flight; in-order
//     vmcnt never drains them inside the loop).
// Structure otherwise = round-11: prep (K/VT fp16 + zero Ctx), pexp (QK^T once,
// p''=2^(s*log2e-4) fp16 relay + partial sums), emit2 (no QK^T/exp/LDS),
// Ctx via unsafeAtomicAdd across 4 key-splits.

typedef _Float16 f16x8 __attribute__((ext_vector_type(8)));
typedef _Float16 f16x4 __attribute__((ext_vector_type(4)));
typedef float f32x4 __attribute__((ext_vector_type(4)));

#define BATCH 8
#define SDIM 2048
#define DDIM 64
#define KBLK 64
#define NBLK (SDIM / KBLK)      // 32
#define KSPLIT 4
#define BPW (NBLK / KSPLIT)     // 8 key-blocks per WG
#define NROWS (BATCH * SDIM)    // 16384
#define QSCALE 0.180336878f     // 0.125 * log2(e): QK^T result is s*log2e
#define EBIAS 4.0f              // p'' = 2^(acc - 4); cancels in normalization
#define KSTR 72                 // LDS row stride in shorts (144 B, 16B-aligned)

__device__ __forceinline__ float fidx(const float4& v, int i) {
    return ((const float*)&v)[i];
}

// ======== K0: K->fp16, V->fp16 transposed, zero Ctx.  256 WGs ========
__global__ __launch_bounds__(256, 4)
void attn_prep(const float* __restrict__ Kg, const float* __restrict__ Vg,
               short* __restrict__ Kbf, short* __restrict__ VTbf,
               float* __restrict__ Ctx)
{
    __shared__ short VTlds[DDIM][KSTR];

    const int wg = blockIdx.x;           // 256 = 8 batches x 32 key-blocks
    const int b = wg & 7;
    const int kbase = (wg >> 3) * KBLK;
    const int tid = threadIdx.x;

    const float* Kb = Kg + (size_t)b * SDIM * DDIM;
    const float* Vb = Vg + (size_t)b * SDIM * DDIM;

    // K convert: thread t -> key=t>>2, 16 d's
    {
        const int key = tid >> 2, doff = (tid & 3) * 16;
        const float* src = Kb + (size_t)(kbase + key) * DDIM + doff;
        float4 f0 = *(const float4*)(src);
        float4 f1 = *(const float4*)(src + 4);
        float4 f2 = *(const float4*)(src + 8);
        float4 f3 = *(const float4*)(src + 12);
        f16x8 p0, p1;
        p0[0]=(_Float16)f0.x; p0[1]=(_Float16)f0.y; p0[2]=(_Float16)f0.z; p0[3]=(_Float16)f0.w;
        p0[4]=(_Float16)f1.x; p0[5]=(_Float16)f1.y; p0[6]=(_Float16)f1.z; p0[7]=(_Float16)f1.w;
        p1[0]=(_Float16)f2.x; p1[1]=(_Float16)f2.y; p1[2]=(_Float16)f2.z; p1[3]=(_Float16)f2.w;
        p1[4]=(_Float16)f3.x; p1[5]=(_Float16)f3.y; p1[6]=(_Float16)f3.z; p1[7]=(_Float16)f3.w;
        short* dst = Kbf + ((size_t)b * SDIM + kbase + key) * DDIM + doff;
        *(f16x8*)dst = p0;
        *(f16x8*)(dst + 8) = p1;
    }

    // V transpose via LDS: thread t loads 4 keys x 4 d's, writes transposed
    {
        const int sv_d0 = (tid & 15) * 4, sv_k0 = (tid >> 4) * 4;
        float4 vreg[4];
        #pragma unroll
        for (int i = 0; i < 4; ++i)
            vreg[i] = *(const float4*)(Vb + (size_t)(kbase + sv_k0 + i) * DDIM + sv_d0);
        #pragma unroll
        for (int dd = 0; dd < 4; ++dd) {
            f16x4 pv;
            pv[0] = (_Float16)fidx(vreg[0], dd);
            pv[1] = (_Float16)fidx(vreg[1], dd);
            pv[2] = (_Float16)fidx(vreg[2], dd);
            pv[3] = (_Float16)fidx(vreg[3], dd);
            *(f16x4*)&VTlds[sv_d0 + dd][sv_k0] = pv;
        }
    }
    __syncthreads();
    {
        const int d = tid >> 2, koff = (tid & 3) * 16;
        f16x8 a = *(const f16x8*)&VTlds[d][koff];
        f16x8 c = *(const f16x8*)&VTlds[d][koff + 8];
        short* dst = VTbf + ((size_t)b * DDIM + d) * SDIM + kbase + koff;
        *(f16x8*)dst = a;
        *(f16x8*)(dst + 8) = c;
    }

    // zero this WG's 16 KB slice of Ctx (4 MB / 256 WGs)
    {
        float4* dst = (float4*)Ctx + (size_t)wg * 1024;
        for (int i = tid; i < 1024; i += 256) dst[i] = make_float4(0.f, 0.f, 0.f, 0.f);
    }
}

// ====== K1: QK^T once -> p'' fp16 relay + partial row sums ======
// Swapped MFMA: C[key=quad*4+r][query=col].
__global__ __launch_bounds__(256, 4)
void attn_pexp(const short* __restrict__ Kbf, const float* __restrict__ Qg,
               const int* __restrict__ Mg, short* __restrict__ Pws,
               float* __restrict__ part)
{
    const int wg = blockIdx.x;
    const int b = wg & 7;
    const int qt = (wg >> 3) & 31;
    const int sp = wg >> 8;
    const int tid = threadIdx.x;
    const int w = tid >> 6, lane = tid & 63, col = lane & 15, quad = lane >> 4;

    // persistent Q fragment (B operand); 0.125*log2e folded in
    f16x8 aq[2];
    {
        const float* qsrc = Qg + ((size_t)b * SDIM + qt * 64 + w * 16 + col) * DDIM + quad * 8;
        #pragma unroll
        for (int c = 0; c < 2; ++c) {
            float4 f0 = *(const float4*)(qsrc + c * 32);
            float4 f1 = *(const float4*)(qsrc + c * 32 + 4);
            f16x8 a;
            a[0]=(_Float16)(f0.x*QSCALE); a[1]=(_Float16)(f0.y*QSCALE); a[2]=(_Float16)(f0.z*QSCALE); a[3]=(_Float16)(f0.w*QSCALE);
            a[4]=(_Float16)(f1.x*QSCALE); a[5]=(_Float16)(f1.y*QSCALE); a[6]=(_Float16)(f1.z*QSCALE); a[7]=(_Float16)(f1.w*QSCALE);
            aq[c] = a;
        }
    }

    const int kb0 = sp * BPW * KBLK;
    const short* Kb = Kbf + (size_t)b * SDIM * DDIM;
    const int*   Mb = Mg + (size_t)b * SDIM;
    // this lane's P'' row (query = col)
    short* Prow = Pws + ((size_t)b * SDIM + qt * 64 + w * 16 + col) * SDIM;

    float lsum = 0.0f;
    for (int kb = 0; kb < BPW; ++kb) {
        const int kbase = kb0 + kb * KBLK;
        f16x8 kf[4][2];
        #pragma unroll
        for (int t = 0; t < 4; ++t) {
            const short* ks = Kb + (size_t)(kbase + t * 16 + col) * DDIM + quad * 8;
            kf[t][0] = *(const f16x8*)ks;
            kf[t][1] = *(const f16x8*)(ks + 32);
        }
        #pragma unroll
        for (int t = 0; t < 4; ++t) {
            f32x4 acc = {0.f, 0.f, 0.f, 0.f};
            acc = __builtin_amdgcn_mfma_f32_16x16x32_f16(kf[t][0], aq[0], acc, 0, 0, 0);
            acc = __builtin_amdgcn_mfma_f32_16x16x32_f16(kf[t][1], aq[1], acc, 0, 0, 0);
            int4 mq = *(const int4*)(Mb + kbase + t * 16 + quad * 4);
            float e0 = mq.x ? 0.0f : exp2f(acc[0] - EBIAS);
            float e1 = mq.y ? 0.0f : exp2f(acc[1] - EBIAS);
            float e2 = mq.z ? 0.0f : exp2f(acc[2] - EBIAS);
            float e3 = mq.w ? 0.0f : exp2f(acc[3] - EBIAS);
            lsum += e0 + e1 + e2 + e3;
            f16x4 pb;
            pb[0] = (_Float16)e0; pb[1] = (_Float16)e1;
            pb[2] = (_Float16)e2; pb[3] = (_Float16)e3;
            // 4 consecutive keys of this query's row -> 8B store (cached relay)
            *(f16x4*)&Prow[kbase + t * 16 + quad * 4] = pb;
        }
    }

    // each lane holds a quarter of this query's keys; sum across quads
    lsum += __shfl_xor(lsum, 16);
    lsum += __shfl_xor(lsum, 32);
    if (quad == 0)
        part[(size_t)sp * NROWS + (size_t)b * SDIM + qt * 64 + w * 16 + col] = lsum;
}

// ======= K2: emit filter + context from the p'' relay (no QK^T, no exp) =======
__global__ __launch_bounds__(256, 4)
void attn_emit2(const short* __restrict__ Pws, const short* __restrict__ VTbf,
                const float* __restrict__ part, float* __restrict__ Ctx,
                float* __restrict__ Filt)
{
    const int wg = blockIdx.x;
    const int b = wg & 7;
    const int qt = (wg >> 3) & 31;
    const int sp = wg >> 8;
    const int tid = threadIdx.x;
    const int w = tid >> 6, lane = tid & 63, col = lane & 15, quad = lane >> 4;

    const short* VTb = VTbf + (size_t)b * DDIM * SDIM;
    float* Ctxb  = Ctx  + (size_t)b * SDIM * DDIM;
    float* Filtb = Filt + (size_t)b * SDIM * SDIM;

    // invl for the Filt row this lane emits (query = col)
    const int qrow_f = qt * 64 + w * 16 + col;
    float invf;
    {
        const size_t row = (size_t)b * SDIM + qrow_f;
        invf = 1.0f / (part[row] + part[NROWS + row] +
                       part[2 * NROWS + row] + part[3 * NROWS + row]);
    }
    // invl for the 4 context rows this lane accumulates (query = quad*4+r)
    float invo[4];
    #pragma unroll
    for (int r = 0; r < 4; ++r) {
        const size_t row = (size_t)b * SDIM + qt * 64 + w * 16 + quad * 4 + r;
        invo[r] = 1.0f / (part[row] + part[NROWS + row] +
                          part[2 * NROWS + row] + part[3 * NROWS + row]);
    }

    const int kb0 = sp * BPW * KBLK;
    const short* Prow = Pws + ((size_t)b * SDIM + qrow_f) * SDIM;

    f32x4 Oacc[4];
    #pragma unroll
    for (int dt = 0; dt < 4; ++dt) Oacc[dt] = (f32x4){0.f, 0.f, 0.f, 0.f};

    for (int kb = 0; kb < BPW; ++kb) {
        const int kbase = kb0 + kb * KBLK;

        // ---- loads first (all ahead of the nt stores, which then stay in
        //      flight: in-order vmcnt never drains them inside the loop) ----
        // store-path mapping (R7-proven full-granule pattern): keys t*16+quad*4
        f16x4 pp4[4];
        #pragma unroll
        for (int t = 0; t < 4; ++t)
            pp4[t] = *(const f16x4*)&Prow[kbase + t * 16 + quad * 4];
        // PV A-operand mapping: keys c*32+quad*8
        f16x8 pp[2];
        #pragma unroll
        for (int c = 0; c < 2; ++c)
            pp[c] = *(const f16x8*)&Prow[kbase + c * 32 + quad * 8];
        f16x8 vt[2][4];
        #pragma unroll
        for (int c = 0; c < 2; ++c)
            #pragma unroll
            for (int dt = 0; dt < 4; ++dt)
                vt[c][dt] = *(const f16x8*)(VTb + (size_t)(dt * 16 + col) * SDIM + kbase + c * 32 + quad * 8);

        // ---- Filt = f32(p'') * invl; 16 rows x contiguous 64B per instr ----
        #pragma unroll
        for (int t = 0; t < 4; ++t) {
            f32x4 p4;
            p4[0] = (float)pp4[t][0] * invf;
            p4[1] = (float)pp4[t][1] * invf;
            p4[2] = (float)pp4[t][2] * invf;
            p4[3] = (float)pp4[t][3] * invf;
            f32x4* fdst = (f32x4*)&Filtb[(size_t)qrow_f * SDIM + kbase + t * 16 + quad * 4];
            __builtin_nontemporal_store(p4, fdst);
        }

        // ---- O += p'' * V (A-operand straight from relay registers) ----
        #pragma unroll
        for (int c = 0; c < 2; ++c) {
            #pragma unroll
            for (int dt = 0; dt < 4; ++dt)
                Oacc[dt] = __builtin_amdgcn_mfma_f32_16x16x32_f16(pp[c], vt[c][dt], Oacc[dt], 0, 0, 0);
        }
    }

    // accumulate context (scale by this row's invl; 4-way split contention)
    #pragma unroll
    for (int dt = 0; dt < 4; ++dt) {
        #pragma unroll
        for (int r = 0; r < 4; ++r) {
            unsafeAtomicAdd(&Ctxb[(size_t)(qt * 64 + w * 16 + quad * 4 + r) * DDIM + dt * 16 + col],
                            Oacc[dt][r] * invo[r]);
        }
    }
}

extern "C" void kernel_launch(void* const* d_in, const int* in_sizes, int n_in,
                              void* d_out, int out_size, void* d_ws, size_t ws_size,
                              hipStream_t stream) {
    // setup_inputs order: key, query, value, query_attention_mask
    const float* Kg = (const float*)d_in[0];
    const float* Qg = (const float*)d_in[1];
    const float* Vg = (const float*)d_in[2];
    const int*   Mg = (const int*)d_in[3];
    float* Ctx  = (float*)d_out;                                   // [8,2048,64]
    float* Filt = (float*)d_out + (size_t)BATCH * SDIM * DDIM;     // [8,2048,2048]

    // workspace: Kbf 2 MB | VTbf 2 MB | part 256 KB | Pws 64 MB
    short* Kbf  = (short*)d_ws;                                    // [8][2048][64] fp16
    short* VTbf = Kbf + (size_t)BATCH * SDIM * DDIM;               // [8][64][2048] fp16
    float* part = (float*)(VTbf + (size_t)BATCH * DDIM * SDIM);    // [4][16384]
    short* Pws  = (short*)(part + (size_t)KSPLIT * NROWS);         // [8][2048][2048] fp16

    attn_prep<<<dim3(BATCH * NBLK), dim3(256), 0, stream>>>(Kg, Vg, Kbf, VTbf, Ctx);
    // 8 batches x 32 qtiles x 4 key-splits = 1024 WGs (sp = wg>>8 decode)
    attn_pexp<<<dim3(BATCH * NBLK * KSPLIT), dim3(256), 0, stream>>>(Kbf, Qg, Mg, Pws, part);
    attn_emit2<<<dim3(BATCH * NBLK * KSPLIT), dim3(256), 0, stream>>>(Pws, VTbf, part, Ctx, Filt);
}